// Round 7
// baseline (106.782 us; speedup 1.0000x reference)
//
#include <hip/hip_runtime.h>

// Performer causal linear attention (generalized relu kernel), fp32 in/out.
// B=1, H=8, N=1024, D=64, M=128. Chunked formulation, chunk C=128:
//   qp = relu(norm * q @ proj^T) + eps ; kp likewise
//   Z  = cumsum_n kp ; W = qp / Z
//   out_c = W_c @ S0_c + tril(W_c @ Kp_c^T) @ V_c ; S0_c = prefix of Kp^T V
// R7: TWO kernels. K1 projg emits bf16 qpb/kpb + fp32 Gp partials + kpart.
// K2 (grid 64x2, 512thr) locally computes S0 (chunk-prefix over Gp, regs),
// W rows (kpart prefix + 64-step z-scan, bf16 -> LDS), then all-MFMA attn.
// No global sync between scan/wdiv/attn needed: all per-(h,c) local.
static constexpr int H = 8, N = 1024, D = 64, M = 128, CHUNK = 128, NC = 8;
static constexpr float EPS = 1e-3f;
static constexpr float NORM = 0.35355339059327373f; // 64^-0.25

typedef __attribute__((ext_vector_type(8))) short short8;
typedef __attribute__((ext_vector_type(4))) float f32x4;

__device__ inline unsigned short f2bf(float x) {
    unsigned u = __float_as_uint(x);
    return (unsigned short)((u + 0x7fffu + ((u >> 16) & 1u)) >> 16);
}
__device__ inline float bf2f(unsigned short u) {
    return __uint_as_float(((unsigned)u) << 16);
}

// -------------------------------- K1: qpb/kpb bf16 (+ G partial, kpart)
// grid (32, H, 2), 256 thr. Block: 32 rows -> 32x128 bf16 outputs;
// k-side also emits Gp[h*32+rblk][M][D] fp32 and kpart[h*32+rblk][M].
__global__ __launch_bounds__(256) void k_projg(const float* __restrict__ q,
                                               const float* __restrict__ k,
                                               const float* __restrict__ proj,
                                               const float* __restrict__ v,
                                               unsigned short* __restrict__ qpb,
                                               unsigned short* __restrict__ kpb,
                                               float* __restrict__ Gp,
                                               float* __restrict__ kpart) {
    __shared__ float plT[64 * 132]; // [d][m]; k-side reuses as kpl[32][132]
    __shared__ float xlT[64 * 36];  // [d][r]; k-side reuses as vl[32][68]
    const int tid = threadIdx.x;
    const int rblk = blockIdx.x;
    const int h = blockIdx.y;
    const int which = blockIdx.z;
    const float* __restrict__ x = which ? k : q;
    unsigned int* __restrict__ dst = (unsigned int*)(which ? kpb : qpb);

    for (int i = tid; i < M * D; i += 256) {
        int m = i >> 6, d = i & 63;
        plT[d * 132 + m] = proj[i];
    }
    const int rowbase = h * N + rblk * 32;
    for (int i = tid; i < 32 * D; i += 256) {
        int r = i >> 6, d = i & 63;
        xlT[d * 36 + r] = x[(rowbase + r) * D + d] * NORM;
    }
    __syncthreads();

    const int m0 = (tid & 31) * 4;
    const int r0 = (tid >> 5) * 4;
    float acc[4][4] = {};
#pragma unroll 8
    for (int d = 0; d < 64; d++) {
        float4 xv = *(const float4*)&xlT[d * 36 + r0];
        float4 pv = *(const float4*)&plT[d * 132 + m0];
        const float xr[4] = {xv.x, xv.y, xv.z, xv.w};
        const float pr[4] = {pv.x, pv.y, pv.z, pv.w};
#pragma unroll
        for (int ri = 0; ri < 4; ri++)
#pragma unroll
            for (int mi = 0; mi < 4; mi++) acc[ri][mi] += xr[ri] * pr[mi];
    }
    float4 sv[4];
#pragma unroll
    for (int ri = 0; ri < 4; ri++) {
        sv[ri].x = fmaxf(acc[ri][0], 0.f) + EPS;
        sv[ri].y = fmaxf(acc[ri][1], 0.f) + EPS;
        sv[ri].z = fmaxf(acc[ri][2], 0.f) + EPS;
        sv[ri].w = fmaxf(acc[ri][3], 0.f) + EPS;
        unsigned int p0 =
            (unsigned)f2bf(sv[ri].x) | ((unsigned)f2bf(sv[ri].y) << 16);
        unsigned int p1 =
            (unsigned)f2bf(sv[ri].z) | ((unsigned)f2bf(sv[ri].w) << 16);
        const int base = (rowbase + r0 + ri) * 64 + (m0 >> 1);
        dst[base] = p0;
        dst[base + 1] = p1;
    }

    if (!which) return;

    // ---- fused per-32-row G partial: G = kp_tile^T (128m) x v_tile (64e)
    __syncthreads();
    float* kpl = plT; // [r][m] stride 132
    float* vl = xlT;  // [r][e] stride 68
#pragma unroll
    for (int ri = 0; ri < 4; ri++)
        *(float4*)&kpl[(r0 + ri) * 132 + m0] = sv[ri];
    for (int i = tid; i < 32 * D; i += 256) {
        int r = i >> 6, e = i & 63;
        vl[r * 68 + e] = v[(rowbase + r) * D + e];
    }
    __syncthreads();

    const int gb = h * 32 + rblk;
    const int mg = (tid >> 3) * 4, eg = (tid & 7) * 8;
    float ag[4][8] = {};
#pragma unroll 4
    for (int nn = 0; nn < 32; nn++) {
        float4 kv = *(const float4*)&kpl[nn * 132 + mg];
        float4 va = *(const float4*)&vl[nn * 68 + eg];
        float4 vb = *(const float4*)&vl[nn * 68 + eg + 4];
        const float kr[4] = {kv.x, kv.y, kv.z, kv.w};
        const float vr[8] = {va.x, va.y, va.z, va.w, vb.x, vb.y, vb.z, vb.w};
#pragma unroll
        for (int mi = 0; mi < 4; mi++)
#pragma unroll
            for (int ej = 0; ej < 8; ej++) ag[mi][ej] += kr[mi] * vr[ej];
    }
#pragma unroll
    for (int mi = 0; mi < 4; mi++) {
        float4 a = {ag[mi][0], ag[mi][1], ag[mi][2], ag[mi][3]};
        float4 bq = {ag[mi][4], ag[mi][5], ag[mi][6], ag[mi][7]};
        *(float4*)&Gp[(gb * M + mg + mi) * D + eg] = a;
        *(float4*)&Gp[(gb * M + mg + mi) * D + eg + 4] = bq;
    }
    if (tid < 128) {
        float ks = 0.f;
#pragma unroll 8
        for (int nn = 0; nn < 32; nn++) ks += kpl[nn * 132 + tid];
        kpart[gb * M + tid] = ks;
    }
}

// ------------- K2: merged scan + wdiv + all-MFMA attention.
// grid (64, 2 halves), 512 thr (8 waves). Per block:
//  0b: W rows (this half) = bf16(qpb/z), z from kpart prefix + 64-step scan.
//  0a: S0 = sum of Gp partials < this chunk, held in regs (16 f32/thread).
//  P1: A = tril(W @ Kp^T) via mfma 16x16x32 bf16 -> Pb in LDS.
//  P2: out = W @ S0 + P @ V via MFMA (S0^T/V^T staged bf16 in LDS).
__global__ __launch_bounds__(512) void k_attn(const unsigned short* __restrict__ qpb,
                                              const unsigned short* __restrict__ kpb,
                                              const float* __restrict__ kpart,
                                              const float* __restrict__ Gp,
                                              const float* __restrict__ v,
                                              float* __restrict__ out) {
    __shared__ __align__(16) short smem[26624]; // 52 KB
    short* bufA = smem;         // W bf16 [64][136]
    short* bufB = smem + 8704;  // Kp [128][72] ph1 / S0T,VT [64][136] ph2
    short* bufC = smem + 17920; // Pb [64][136]
    const int tid = threadIdx.x;
    const int b = blockIdx.x;
    const int half = blockIdx.y;
    const int h = b >> 3, c = 7 - (b & 7); // heavy (large-c) blocks first
    const int chunkbase = h * N + c * CHUNK;
    const int rowbase = chunkbase + half * 64;
    const int lane = tid & 63, wv = tid >> 6; // wv 0..7
    const int wr_ = wv & 3, wj = wv >> 2;     // row-group / tile-half
    const int fr = lane & 15, fq = lane >> 4;

    // ---- 0b: W rows for this half -> bufA (threads 0..127, one per m)
    if (tid < 128) {
        const int m = tid;
        float z = 0.f;
        const int send = c * 4 + half * 2;
        for (int s = 0; s < send; s++) z += kpart[(h * 32 + s) * M + m];
#pragma unroll 4
        for (int r = 0; r < 64; r++) {
            z += bf2f(kpb[(rowbase + r) * M + m]);
            float w = bf2f(qpb[(rowbase + r) * M + m]) * __builtin_amdgcn_rcpf(z);
            bufA[r * 136 + m] = (short)f2bf(w);
        }
    }
    // ---- 0a: S0 chunk-prefix into regs (all threads; 16 el each)
    float s0r[16];
#pragma unroll
    for (int j = 0; j < 16; j++) s0r[j] = 0.f;
    {
        const int ibase = tid * 16;
        for (int cp = 0; cp < c; cp++) {
#pragma unroll
            for (int p = 0; p < 4; p++) {
                const float* gsrc = &Gp[(h * 32 + cp * 4 + p) * (M * D) + ibase];
#pragma unroll
                for (int j4 = 0; j4 < 4; j4++) {
                    float4 g = *(const float4*)&gsrc[j4 * 4];
                    s0r[j4 * 4 + 0] += g.x;
                    s0r[j4 * 4 + 1] += g.y;
                    s0r[j4 * 4 + 2] += g.z;
                    s0r[j4 * 4 + 3] += g.w;
                }
            }
        }
    }
    __syncthreads(); // bufA (W) ready

    // ---- P1: A = tril(W @ Kp^T). Waves split: rows by wr_, j-half by wj.
    f32x4 acc1[4];
#pragma unroll
    for (int jt = 0; jt < 4; jt++) acc1[jt] = (f32x4){0.f, 0.f, 0.f, 0.f};
    for (int kh = 0; kh < 2; kh++) {
        if (kh) __syncthreads();
        {
            const unsigned int* src = (const unsigned int*)kpb;
            for (int i = tid; i < 128 * 32; i += 512) {
                int j = i >> 5, mu = i & 31;
                ((unsigned int*)&bufB[j * 72])[mu] =
                    src[(chunkbase + j) * 64 + kh * 32 + mu];
            }
        }
        __syncthreads();
        if (half || wj == 0) { // half 0: j>=64 fully masked -> skip wj==1
#pragma unroll
            for (int kt2 = 0; kt2 < 2; kt2++) {
                short8 a = *(const short8*)&bufA[(16 * wr_ + fr) * 136 + kh * 64 +
                                                 kt2 * 32 + fq * 8];
#pragma unroll
                for (int jl = 0; jl < 4; jl++) {
                    const int jt = wj * 4 + jl;
                    short8 bb =
                        *(const short8*)&bufB[(16 * jt + fr) * 72 + kt2 * 32 + fq * 8];
                    acc1[jl] =
                        __builtin_amdgcn_mfma_f32_16x16x32_bf16(a, bb, acc1[jl], 0, 0, 0);
                }
            }
        }
    }
    // mask (tril incl diag) + C/D -> A-operand relayout via LDS (bf16)
#pragma unroll
    for (int jl = 0; jl < 4; jl++) {
        const int jt = wj * 4 + jl;
        const int j = 16 * jt + fr;
#pragma unroll
        for (int reg = 0; reg < 4; reg++) {
            const int nloc = 16 * wr_ + fq * 4 + reg;
            float val =
                ((half || jt < 4) && j <= half * 64 + nloc) ? acc1[jl][reg] : 0.f;
            bufC[nloc * 136 + j] = (short)f2bf(val);
        }
    }
    __syncthreads(); // bufB reads done, bufC complete

    // ---- stage S0^T bf16 from regs: bufB[e][136] = S0[m][e]
    {
        const int m = tid >> 2;
        const int ebase = (tid & 3) * 16;
#pragma unroll
        for (int j = 0; j < 16; j++)
            bufB[(ebase + j) * 136 + m] = (short)f2bf(s0r[j]);
    }
    __syncthreads();

    // ---- P2a: out = W @ S0 (K=128). Waves: rows by wr_, e-half by wj.
    f32x4 acc2[2];
    acc2[0] = (f32x4){0.f, 0.f, 0.f, 0.f};
    acc2[1] = (f32x4){0.f, 0.f, 0.f, 0.f};
#pragma unroll
    for (int kt = 0; kt < 4; kt++) {
        short8 a = *(const short8*)&bufA[(16 * wr_ + fr) * 136 + kt * 32 + fq * 8];
#pragma unroll
        for (int el = 0; el < 2; el++) {
            const int et = wj * 2 + el;
            short8 bb = *(const short8*)&bufB[(16 * et + fr) * 136 + kt * 32 + fq * 8];
            acc2[el] = __builtin_amdgcn_mfma_f32_16x16x32_bf16(a, bb, acc2[el], 0, 0, 0);
        }
    }
    __syncthreads(); // S0T reads done

    // ---- stage V^T bf16: bufB[e][136] = v[j][e]
    for (int i = tid; i < 128 * 16; i += 512) {
        int j = i >> 4, e4 = (i & 15) * 4;
        float4 g = *(const float4*)&v[(chunkbase + j) * 64 + e4];
        bufB[(e4 + 0) * 136 + j] = (short)f2bf(g.x);
        bufB[(e4 + 1) * 136 + j] = (short)f2bf(g.y);
        bufB[(e4 + 2) * 136 + j] = (short)f2bf(g.z);
        bufB[(e4 + 3) * 136 + j] = (short)f2bf(g.w);
    }
    __syncthreads();

    // ---- P2b: out += P @ V. half 0: Pb cols j>=64 are zero -> K=64.
    const int ktmax = half ? 4 : 2;
    for (int kt = 0; kt < ktmax; kt++) {
        short8 a = *(const short8*)&bufC[(16 * wr_ + fr) * 136 + kt * 32 + fq * 8];
#pragma unroll
        for (int el = 0; el < 2; el++) {
            const int et = wj * 2 + el;
            short8 bb = *(const short8*)&bufB[(16 * et + fr) * 136 + kt * 32 + fq * 8];
            acc2[el] = __builtin_amdgcn_mfma_f32_16x16x32_bf16(a, bb, acc2[el], 0, 0, 0);
        }
    }

    // ---- epilogue: C/D layout -> global fp32
#pragma unroll
    for (int el = 0; el < 2; el++) {
        const int et = wj * 2 + el;
#pragma unroll
        for (int reg = 0; reg < 4; reg++) {
            out[(rowbase + 16 * wr_ + fq * 4 + reg) * D + 16 * et + fr] =
                acc2[el][reg];
        }
    }
}

extern "C" void kernel_launch(void* const* d_in, const int* in_sizes, int n_in,
                              void* d_out, int out_size, void* d_ws, size_t ws_size,
                              hipStream_t stream) {
    const float* q = (const float*)d_in[0];
    const float* k = (const float*)d_in[1];
    const float* v = (const float*)d_in[2];
    const float* proj = (const float*)d_in[3];
    float* out = (float*)d_out;

    // workspace: Gp 8MB fp32, kpart 128KB fp32, qpb/kpb 2MB bf16 each
    float* ws = (float*)d_ws;
    float* Gp = ws;                                      // H*32*M*D
    float* kpart = Gp + H * 32 * M * D;                  // H*32*M
    unsigned short* qpb = (unsigned short*)(kpart + H * 32 * M); // H*N*M
    unsigned short* kpb = qpb + H * N * M;                       // H*N*M

    k_projg<<<dim3(32, H, 2), 256, 0, stream>>>(q, k, proj, v, qpb, kpb, Gp,
                                                kpart);
    k_attn<<<dim3(H * NC, 2), 512, 0, stream>>>(qpb, kpb, kpart, Gp, v, out);
}

// Round 8
// 89.730 us; speedup vs baseline: 1.1900x; 1.1900x over previous
//
#include <hip/hip_runtime.h>

// Performer causal linear attention (generalized relu kernel), fp32 in/out.
// B=1, H=8, N=1024, D=64, M=128. Chunked formulation, chunk C=128:
//   qp = relu(norm * q @ proj^T) + eps ; kp likewise
//   Z  = cumsum_n kp ; W = qp / Z
//   out_c = W_c @ S0_c + tril(W_c @ Kp_c^T) @ V_c ; S0_c = prefix of Kp^T V
// R8: all-MFMA both kernels. K1: proj GEMM + G partial via mfma bf16 (proj/x
// are natively in MFMA A/B layout; G via LDS-transposed kp/v), Gp stored
// bf16. K2: 256 blocks (64 hc x 4 sub-blocks of 32 rows) so all CUs busy;
// serial z-scan 32 with register prefetch; full-K Kp staging; 6 barriers;
// causal tile skipping (jtmax=2sub+2, ktmax=sub+1).
static constexpr int H = 8, N = 1024, D = 64, M = 128, CHUNK = 128, NC = 8;
static constexpr float EPS = 1e-3f;
static constexpr float NORM = 0.35355339059327373f; // 64^-0.25

typedef __attribute__((ext_vector_type(8))) short short8;
typedef __attribute__((ext_vector_type(4))) float f32x4;

__device__ inline unsigned short f2bf(float x) {
    unsigned u = __float_as_uint(x);
    return (unsigned short)((u + 0x7fffu + ((u >> 16) & 1u)) >> 16);
}
__device__ inline float bf2f(unsigned short u) {
    return __uint_as_float(((unsigned)u) << 16);
}
__device__ inline ushort4 pack4(float4 g) {
    return (ushort4){f2bf(g.x), f2bf(g.y), f2bf(g.z), f2bf(g.w)};
}

// -------- K1: qpb/kpb = bf16(relu(norm x @ proj^T)+eps); k-side also Gpb
// (bf16 32-row partial of Kp^T V) and kpart. grid (32, H, 2), 256 thr.
__global__ __launch_bounds__(256) void k_projg(const float* __restrict__ q,
                                               const float* __restrict__ k,
                                               const float* __restrict__ proj,
                                               const float* __restrict__ v,
                                               unsigned short* __restrict__ qpb,
                                               unsigned short* __restrict__ kpb,
                                               unsigned short* __restrict__ Gpb,
                                               float* __restrict__ kpart) {
    __shared__ __align__(16) short smem[19200]; // 38.4 KB
    short* projb = smem;         // [m 128][72]  B-operand (row=outcol, col=K)
    short* xb = smem + 9216;     // [r 32][72]   A-operand
    short* kpT = smem + 11520;   // [m 128][40]  A-operand for G
    short* vT = smem + 16640;    // [e 64][40]   B-operand for G
    const int tid = threadIdx.x;
    const int rblk = blockIdx.x;
    const int h = blockIdx.y;
    const int which = blockIdx.z;
    const float* __restrict__ x = which ? k : q;
    unsigned short* __restrict__ dst = which ? kpb : qpb;
    const int rowbase = h * N + rblk * 32;
    const int lane = tid & 63, wv = tid >> 6;
    const int rt = wv & 1, mh = wv >> 1;
    const int fr = lane & 15, fq = lane >> 4;

    // stage proj -> bf16 [m][72]
    for (int i4 = tid; i4 < 2048; i4 += 256) {
        int m = i4 >> 4, dq = i4 & 15;
        float4 g = *(const float4*)&proj[i4 * 4];
        *(ushort4*)&projb[m * 72 + dq * 4] = pack4(g);
    }
    // stage x*NORM -> bf16 [r][72]
    for (int i4 = tid; i4 < 512; i4 += 256) {
        int r = i4 >> 4, dq = i4 & 15;
        float4 g = *(const float4*)&x[(rowbase + r) * D + dq * 4];
        g.x *= NORM; g.y *= NORM; g.z *= NORM; g.w *= NORM;
        *(ushort4*)&xb[r * 72 + dq * 4] = pack4(g);
    }
    // k-side: stage v^T -> bf16 [e][40]
    if (which) {
        for (int i4 = tid; i4 < 512; i4 += 256) {
            int r = i4 & 31, e4 = (i4 >> 5) * 4;
            float4 g = *(const float4*)&v[(rowbase + r) * D + e4];
            vT[(e4 + 0) * 40 + r] = (short)f2bf(g.x);
            vT[(e4 + 1) * 40 + r] = (short)f2bf(g.y);
            vT[(e4 + 2) * 40 + r] = (short)f2bf(g.z);
            vT[(e4 + 3) * 40 + r] = (short)f2bf(g.w);
        }
    }
    __syncthreads();

    // proj GEMM: 32 rows x 128 m, K=64. wave (rt, mh): 4 m-tiles x 2 kt.
    f32x4 accp[4];
#pragma unroll
    for (int i = 0; i < 4; i++) accp[i] = (f32x4){0.f, 0.f, 0.f, 0.f};
#pragma unroll
    for (int kt = 0; kt < 2; kt++) {
        short8 a = *(const short8*)&xb[(16 * rt + fr) * 72 + kt * 32 + fq * 8];
#pragma unroll
        for (int i = 0; i < 4; i++) {
            const int mt = mh * 4 + i;
            short8 bb = *(const short8*)&projb[(16 * mt + fr) * 72 + kt * 32 + fq * 8];
            accp[i] = __builtin_amdgcn_mfma_f32_16x16x32_bf16(a, bb, accp[i], 0, 0, 0);
        }
    }
    // epilogue: relu+eps -> global bf16 (+ kpT LDS on k-side)
#pragma unroll
    for (int i = 0; i < 4; i++) {
        const int mt = mh * 4 + i;
#pragma unroll
        for (int reg = 0; reg < 4; reg++) {
            const int r = 16 * rt + fq * 4 + reg; // local row
            const int m = 16 * mt + fr;
            unsigned short bv = f2bf(fmaxf(accp[i][reg], 0.f) + EPS);
            dst[(rowbase + r) * M + m] = bv;
            if (which) kpT[m * 40 + r] = (short)bv;
        }
    }
    if (!which) return;
    __syncthreads();

    // G = Kp^T V: 128 m x 64 e, K=32 (single MFMA step). wave: 2 m-tiles.
    const int gb = h * 32 + rblk;
    f32x4 gacc[2][4];
#pragma unroll
    for (int i = 0; i < 2; i++)
#pragma unroll
        for (int et = 0; et < 4; et++) gacc[i][et] = (f32x4){0.f, 0.f, 0.f, 0.f};
#pragma unroll
    for (int i = 0; i < 2; i++) {
        const int mt = wv * 2 + i;
        short8 a = *(const short8*)&kpT[(16 * mt + fr) * 40 + fq * 8];
#pragma unroll
        for (int et = 0; et < 4; et++) {
            short8 bb = *(const short8*)&vT[(16 * et + fr) * 40 + fq * 8];
            gacc[i][et] =
                __builtin_amdgcn_mfma_f32_16x16x32_bf16(a, bb, gacc[i][et], 0, 0, 0);
        }
    }
#pragma unroll
    for (int i = 0; i < 2; i++) {
        const int mt = wv * 2 + i;
#pragma unroll
        for (int et = 0; et < 4; et++)
#pragma unroll
            for (int reg = 0; reg < 4; reg++) {
                const int m = 16 * mt + fq * 4 + reg;
                const int e = 16 * et + fr;
                Gpb[(gb * M + m) * D + e] = f2bf(gacc[i][et][reg]);
            }
    }
    // kpart: column sums of this 32-row kp tile
    if (tid < 128) {
        float ks = 0.f;
#pragma unroll 8
        for (int r = 0; r < 32; r++) ks += bf2f(kpT[tid * 40 + r]);
        kpart[gb * M + tid] = ks;
    }
}

// -------- K2: grid (64, 4 subs), 512 thr. Per block: 32 output rows.
//  0: Kp full-chunk staging; W z-scan (regs prefetch, serial 32); S0 regs.
//  P1: A = tril(W @ Kp^T) (jt tiles skipped past causal edge) -> Pb LDS.
//  P2: out = W @ S0 + P @ V (S0T/VT staged over Kp region).
__global__ __launch_bounds__(512) void k_attn(const unsigned short* __restrict__ qpb,
                                              const unsigned short* __restrict__ kpb,
                                              const float* __restrict__ kpart,
                                              const unsigned short* __restrict__ Gpb,
                                              const float* __restrict__ v,
                                              float* __restrict__ out) {
    __shared__ __align__(16) short smem[26112]; // 52.2 KB
    short* bufA = smem;          // W  [32][136]
    short* bufB = smem + 4352;   // Kp [128][136]; later S0T/VT [64][136]
    short* bufC = smem + 21760;  // Pb [32][136]
    const int tid = threadIdx.x;
    const int b = blockIdx.x;
    const int sub = blockIdx.y; // 0..3, 32-row sub-block
    const int h = b >> 3, c = 7 - (b & 7);
    const int chunkbase = h * N + c * CHUNK;
    const int rowstart = chunkbase + sub * 32;
    const int lane = tid & 63, wv = tid >> 6;
    const int rt = wv & 1, js = wv >> 1; // row-tile / col-tile-group
    const int fr = lane & 15, fq = lane >> 4;

    // ---- stage Kp chunk (128 x 128 bf16, full K)
    {
        const unsigned int* src = (const unsigned int*)kpb;
        for (int i = tid; i < 8192; i += 512) {
            int j = i >> 6, mu = i & 63;
            ((unsigned int*)&bufB[j * 136])[mu] = src[(chunkbase + j) * 64 + mu];
        }
    }
    // ---- W rows: z-scan serial 32 (rows prefetched to regs)
    if (tid < 128) {
        const int m = tid;
        float z = 0.f;
        const int send = c * 4 + sub;
        for (int s = 0; s < send; s++) z += kpart[(h * 32 + s) * M + m];
        unsigned short kr_[32], qr_[32];
#pragma unroll
        for (int r = 0; r < 32; r++) {
            kr_[r] = kpb[(rowstart + r) * M + m];
            qr_[r] = qpb[(rowstart + r) * M + m];
        }
#pragma unroll
        for (int r = 0; r < 32; r++) {
            z += bf2f(kr_[r]);
            bufA[r * 136 + m] =
                (short)f2bf(bf2f(qr_[r]) * __builtin_amdgcn_rcpf(z));
        }
    }
    // ---- S0 chunk-prefix into regs (16 f32/thread)
    float s0r[16];
#pragma unroll
    for (int j = 0; j < 16; j++) s0r[j] = 0.f;
    for (int cp = 0; cp < c; cp++) {
#pragma unroll
        for (int p = 0; p < 4; p++) {
            const short* gsrc =
                (const short*)&Gpb[(h * 32 + cp * 4 + p) * (M * D) + tid * 16];
            short8 g0 = *(const short8*)&gsrc[0];
            short8 g1 = *(const short8*)&gsrc[8];
#pragma unroll
            for (int j = 0; j < 8; j++) {
                s0r[j] += bf2f((unsigned short)g0[j]);
                s0r[8 + j] += bf2f((unsigned short)g1[j]);
            }
        }
    }
    __syncthreads();

    // ---- P1: A = tril(W @ Kp^T), rows 32, cols up to (sub+1)*32
    const int jtmax = 2 * sub + 2;
    f32x4 acc1[2];
    acc1[0] = (f32x4){0.f, 0.f, 0.f, 0.f};
    acc1[1] = (f32x4){0.f, 0.f, 0.f, 0.f};
#pragma unroll
    for (int kt = 0; kt < 4; kt++) {
        short8 a = *(const short8*)&bufA[(16 * rt + fr) * 136 + kt * 32 + fq * 8];
#pragma unroll
        for (int jl = 0; jl < 2; jl++) {
            const int jt = 2 * js + jl;
            if (jt < jtmax) {
                short8 bb =
                    *(const short8*)&bufB[(16 * jt + fr) * 136 + kt * 32 + fq * 8];
                acc1[jl] =
                    __builtin_amdgcn_mfma_f32_16x16x32_bf16(a, bb, acc1[jl], 0, 0, 0);
            }
        }
    }
    // mask + C/D -> A-operand relayout into bufC
#pragma unroll
    for (int jl = 0; jl < 2; jl++) {
        const int jt = 2 * js + jl;
        if (jt < jtmax) {
            const int j = 16 * jt + fr;
#pragma unroll
            for (int reg = 0; reg < 4; reg++) {
                const int nloc = 16 * rt + fq * 4 + reg;
                float val = (j <= sub * 32 + nloc) ? acc1[jl][reg] : 0.f;
                bufC[nloc * 136 + j] = (short)f2bf(val);
            }
        }
    }
    __syncthreads(); // Kp reads done; Pb writes issued

    // ---- stage S0^T from regs: bufB[e][136] = S0[m][e]
    {
        const int m = tid >> 2;
        const int ebase = (tid & 3) * 16;
#pragma unroll
        for (int j = 0; j < 16; j++)
            bufB[(ebase + j) * 136 + m] = (short)f2bf(s0r[j]);
    }
    __syncthreads();

    // ---- P2a: out = W @ S0 (K=128); wave (rt, et=js)
    f32x4 acc2 = (f32x4){0.f, 0.f, 0.f, 0.f};
#pragma unroll
    for (int kt = 0; kt < 4; kt++) {
        short8 a = *(const short8*)&bufA[(16 * rt + fr) * 136 + kt * 32 + fq * 8];
        short8 bb = *(const short8*)&bufB[(16 * js + fr) * 136 + kt * 32 + fq * 8];
        acc2 = __builtin_amdgcn_mfma_f32_16x16x32_bf16(a, bb, acc2, 0, 0, 0);
    }
    __syncthreads(); // S0T reads done

    // ---- stage V^T: bufB[e][136] = v[j][e]
    for (int i = tid; i < 2048; i += 512) {
        int j = i >> 4, e4 = (i & 15) * 4;
        float4 g = *(const float4*)&v[(chunkbase + j) * D + e4];
        bufB[(e4 + 0) * 136 + j] = (short)f2bf(g.x);
        bufB[(e4 + 1) * 136 + j] = (short)f2bf(g.y);
        bufB[(e4 + 2) * 136 + j] = (short)f2bf(g.z);
        bufB[(e4 + 3) * 136 + j] = (short)f2bf(g.w);
    }
    __syncthreads();

    // ---- P2b: out += P @ V (K limited to (sub+1)*32 by causality)
    const int ktmax = sub + 1;
    for (int kt = 0; kt < ktmax; kt++) {
        short8 a = *(const short8*)&bufC[(16 * rt + fr) * 136 + kt * 32 + fq * 8];
        short8 bb = *(const short8*)&bufB[(16 * js + fr) * 136 + kt * 32 + fq * 8];
        acc2 = __builtin_amdgcn_mfma_f32_16x16x32_bf16(a, bb, acc2, 0, 0, 0);
    }

    // ---- epilogue
#pragma unroll
    for (int reg = 0; reg < 4; reg++) {
        out[(rowstart + 16 * rt + fq * 4 + reg) * D + 16 * js + fr] = acc2[reg];
    }
}

extern "C" void kernel_launch(void* const* d_in, const int* in_sizes, int n_in,
                              void* d_out, int out_size, void* d_ws, size_t ws_size,
                              hipStream_t stream) {
    const float* q = (const float*)d_in[0];
    const float* k = (const float*)d_in[1];
    const float* v = (const float*)d_in[2];
    const float* proj = (const float*)d_in[3];
    float* out = (float*)d_out;

    // workspace: kpart 128KB fp32; qpb/kpb 2MB bf16; Gpb 4MB bf16
    float* ws = (float*)d_ws;
    float* kpart = ws;                                      // H*32*M
    unsigned short* qpb = (unsigned short*)(kpart + H * 32 * M); // H*N*M
    unsigned short* kpb = qpb + H * N * M;                       // H*N*M
    unsigned short* Gpb = kpb + H * N * M;                       // H*32*M*D

    k_projg<<<dim3(32, H, 2), 256, 0, stream>>>(q, k, proj, v, qpb, kpb, Gpb,
                                                kpart);
    k_attn<<<dim3(H * NC, 4), 512, 0, stream>>>(qpb, kpb, kpart, Gpb, v, out);
}